// Round 1
// baseline (533.531 us; speedup 1.0000x reference)
//
#include <hip/hip_runtime.h>
#include <hip/hip_bf16.h>
#include <stdint.h>

#define B_ 4
#define T_ 2048
#define S_ 512
#define HID_ 2048
#define ND_ 1024
#define NH_ 16
#define HD_ 128

typedef unsigned short u16;
typedef __attribute__((ext_vector_type(8))) short bf16x8;
typedef __attribute__((ext_vector_type(4))) float f32x4;
typedef __attribute__((ext_vector_type(4))) float f4;
typedef __attribute__((ext_vector_type(4))) u16 us4;
typedef __attribute__((ext_vector_type(8))) u16 us8;

__device__ inline u16 f2bf(float f) {
  unsigned u = __builtin_bit_cast(unsigned, f);
  u += 0x7FFFu + ((u >> 16) & 1u);   // round-to-nearest-even
  return (u16)(u >> 16);
}

__device__ inline f32x4 mfma16(bf16x8 a, bf16x8 b, f32x4 c) {
  return __builtin_amdgcn_mfma_f32_16x16x32_bf16(a, b, c, 0, 0, 0);
}

__device__ inline void gload_lds16(const u16* g, u16* l) {
  __builtin_amdgcn_global_load_lds(
      (const __attribute__((address_space(1))) unsigned int*)g,
      (__attribute__((address_space(3))) unsigned int*)l, 16, 0, 0);
}

// ---------------- fp32 -> bf16 conversion for all operands ----------------
__global__ __launch_bounds__(256) void convert_all(
    const float* __restrict__ h, const float* __restrict__ n,
    const float* __restrict__ qw, const float* __restrict__ kw,
    const float* __restrict__ vw, const float* __restrict__ ow,
    u16* __restrict__ dh, u16* __restrict__ dn, u16* __restrict__ dqw,
    u16* __restrict__ dkw, u16* __restrict__ dvw, u16* __restrict__ dow) {
  // float4-chunk counts (all sizes divisible by 4)
  const int C0 = 4194304;            // hidden 16.78M
  const int C1 = C0 + 524288;        // notes 2.10M
  const int C2 = C1 + 1048576;       // q_w 4.19M
  const int C3 = C2 + 524288;        // k_w 2.10M
  const int C4 = C3 + 524288;        // v_w 2.10M
  const int C5 = C4 + 1048576;       // o_w 4.19M
  for (int c = blockIdx.x * blockDim.x + threadIdx.x; c < C5;
       c += gridDim.x * blockDim.x) {
    const float* s; u16* d; int o;
    if (c < C0)      { s = h;  d = dh;  o = c; }
    else if (c < C1) { s = n;  d = dn;  o = c - C0; }
    else if (c < C2) { s = qw; d = dqw; o = c - C1; }
    else if (c < C3) { s = kw; d = dkw; o = c - C2; }
    else if (c < C4) { s = vw; d = dvw; o = c - C3; }
    else             { s = ow; d = dow; o = c - C4; }
    f4 v = ((const f4*)s)[o];
    us4 r = { f2bf(v[0]), f2bf(v[1]), f2bf(v[2]), f2bf(v[3]) };
    ((us4*)d)[o] = r;
  }
}

// ---------------- GEMM: C(M,N) = A(M,K) @ B(N,K)^T + bias ----------------
// 128x128 tile, BK=32, 4 waves (2x2 of 64x64), 16x16x32 bf16 MFMA,
// global_load_lds width-16 staging (m97 structure).
template <bool OUT_BF16>
__global__ __launch_bounds__(256) void gemm_bt(
    const u16* __restrict__ A, const u16* __restrict__ Bm,
    const float* __restrict__ bias, void* __restrict__ Cout,
    int M, int N, int K) {
  __shared__ u16 As[128 * 32];
  __shared__ u16 Bs[128 * 32];
  const int tid = threadIdx.x;
  const int lane = tid & 63;
  const int wave = tid >> 6;
  const int wr = (wave >> 1) * 64;
  const int wc = (wave & 1) * 64;
  const int c15 = lane & 15;
  const int g = lane >> 4;
  const int bx = blockIdx.x, by = blockIdx.y;

  const u16* gA = A + (size_t)(by * 128 + (tid >> 2)) * K + (tid & 3) * 8;
  const u16* gB = Bm + (size_t)(bx * 128 + (tid >> 2)) * K + (tid & 3) * 8;

  f32x4 acc[4][4];
#pragma unroll
  for (int i = 0; i < 4; ++i)
#pragma unroll
    for (int j = 0; j < 4; ++j) acc[i][j] = (f32x4){0.f, 0.f, 0.f, 0.f};

  for (int k0 = 0; k0 < K; k0 += 32) {
    // stage A,B tiles: chunk c = i*256 + tid -> LDS row c/4, col (c%4)*8
    gload_lds16(gA + k0, &As[wave * 512]);
    gload_lds16(gA + (size_t)64 * K + k0, &As[2048 + wave * 512]);
    gload_lds16(gB + k0, &Bs[wave * 512]);
    gload_lds16(gB + (size_t)64 * K + k0, &Bs[2048 + wave * 512]);
    __syncthreads();   // drains vmcnt before barrier (compiler-enforced)
    bf16x8 af[4], bfr[4];
#pragma unroll
    for (int mt = 0; mt < 4; ++mt)
      af[mt] = *(const bf16x8*)&As[(wr + mt * 16 + c15) * 32 + g * 8];
#pragma unroll
    for (int nt = 0; nt < 4; ++nt)
      bfr[nt] = *(const bf16x8*)&Bs[(wc + nt * 16 + c15) * 32 + g * 8];
#pragma unroll
    for (int mt = 0; mt < 4; ++mt)
#pragma unroll
      for (int nt = 0; nt < 4; ++nt)
        acc[mt][nt] = mfma16(af[mt], bfr[nt], acc[mt][nt]);
    __syncthreads();
  }

#pragma unroll
  for (int mt = 0; mt < 4; ++mt)
#pragma unroll
    for (int nt = 0; nt < 4; ++nt) {
      const int m = by * 128 + wr + mt * 16 + g * 4;
      const int n = bx * 128 + wc + nt * 16 + c15;
      const float bv = bias[n];
#pragma unroll
      for (int r = 0; r < 4; ++r) {
        const float v = acc[mt][nt][r] + bv;
        if (OUT_BF16)
          ((u16*)Cout)[(size_t)(m + r) * N + n] = f2bf(v);
        else
          ((float*)Cout)[(size_t)(m + r) * N + n] = v;
      }
    }
}

// ---------------- V transpose: (B,S,H,D) -> (B,H,D,S) ----------------
__global__ __launch_bounds__(256) void transpose_v(const u16* __restrict__ v,
                                                   u16* __restrict__ vt) {
  __shared__ u16 tile[32][36];   // 36: 72B row stride keeps 8B alignment
  const int s0 = blockIdx.x * 32;
  const int bh = blockIdx.y;
  const int d0 = blockIdx.z * 32;
  const int b = bh >> 4, h = bh & 15;
  const int tid = threadIdx.x;
  const int sl = tid >> 3, dl = (tid & 7) * 4;
  us4 val = *(const us4*)(v + (size_t)(b * S_ + s0 + sl) * HID_ + h * HD_ + d0 + dl);
  *(us4*)&tile[sl][dl] = val;
  __syncthreads();
  const int dl2 = tid >> 3, sl2 = (tid & 7) * 4;
  us4 outv = { tile[sl2 + 0][dl2], tile[sl2 + 1][dl2],
               tile[sl2 + 2][dl2], tile[sl2 + 3][dl2] };
  *(us4*)(vt + ((size_t)bh * HD_ + d0 + dl2) * S_ + s0 + sl2) = outv;
}

// ---------------- fused masked cross-attention (flash-style) ----------------
// block = 4 waves; wave owns 16 q-rows. Scores computed as S^T = mfma(K,Q)
// so t = lane&15; ctx accumulated as ctx^T = mfma(V^T, P^T) (same home).
__global__ __launch_bounds__(256) void attn_fwd(
    const u16* __restrict__ q, const u16* __restrict__ k,
    const u16* __restrict__ vt, const int* __restrict__ mask,
    const float* __restrict__ gate, u16* __restrict__ ctx) {
  __shared__ float addend[S_];          // mask -> additive -1e30
  __shared__ u16 p_lds[4][16][32];      // per-wave P tile
  __shared__ u16 c_lds[4][16][128];     // per-wave epilogue transpose
  const int tid = threadIdx.x, lane = tid & 63, wave = tid >> 6;
  const int bh = blockIdx.y, b = bh >> 4, h = bh & 15;
  const int t0 = blockIdx.x * 64 + wave * 16;
  const int c15 = lane & 15, g = lane >> 4;

  for (int s = tid; s < S_; s += 256)
    addend[s] = mask[b * S_ + s] ? 0.f : -1e30f;
  __syncthreads();

  // Q fragments (B-operand): col t = c15, k-dim d = dc*32 + g*8 + j
  const u16* qrow = q + (size_t)(b * T_ + t0 + c15) * HID_ + h * HD_;
  bf16x8 qf[4];
#pragma unroll
  for (int dc = 0; dc < 4; ++dc)
    qf[dc] = *(const bf16x8*)&qrow[dc * 32 + g * 8];

  const u16* kb = k + (size_t)b * S_ * HID_ + h * HD_;
  const u16* vb = vt + (size_t)bh * HD_ * S_;

  float m_run = -1e30f, l_run = 0.f;
  f32x4 ct[8];
#pragma unroll
  for (int i = 0; i < 8; ++i) ct[i] = (f32x4){0.f, 0.f, 0.f, 0.f};
  const float scale = 0.08838834764831845f;  // 1/sqrt(128)

  for (int it = 0; it < 16; ++it) {
    const int s0 = it * 32;
    f32x4 st0 = {0.f, 0.f, 0.f, 0.f}, st1 = {0.f, 0.f, 0.f, 0.f};
#pragma unroll
    for (int dc = 0; dc < 4; ++dc) {
      bf16x8 ka0 = *(const bf16x8*)&kb[(size_t)(s0 + c15) * HID_ + dc * 32 + g * 8];
      bf16x8 ka1 = *(const bf16x8*)&kb[(size_t)(s0 + 16 + c15) * HID_ + dc * 32 + g * 8];
      st0 = mfma16(ka0, qf[dc], st0);   // S^T[s][t], s = s0 + 4g + r
      st1 = mfma16(ka1, qf[dc], st1);   // s = s0 + 16 + 4g + r
    }
    float sc[8];
#pragma unroll
    for (int r = 0; r < 4; ++r) {
      sc[r]     = st0[r] * scale + addend[s0 + g * 4 + r];
      sc[4 + r] = st1[r] * scale + addend[s0 + 16 + g * 4 + r];
    }
    float tm = sc[0];
#pragma unroll
    for (int i = 1; i < 8; ++i) tm = fmaxf(tm, sc[i]);
    tm = fmaxf(tm, __shfl_xor(tm, 16));
    tm = fmaxf(tm, __shfl_xor(tm, 32));
    const float new_m = fmaxf(m_run, tm);
    const float corr = __expf(m_run - new_m);
    m_run = new_m;
    float p[8], ps = 0.f;
#pragma unroll
    for (int i = 0; i < 8; ++i) { p[i] = __expf(sc[i] - new_m); ps += p[i]; }
    ps += __shfl_xor(ps, 16);
    ps += __shfl_xor(ps, 32);
    l_run = l_run * corr + ps;
#pragma unroll
    for (int dt = 0; dt < 8; ++dt)
#pragma unroll
      for (int r = 0; r < 4; ++r) ct[dt][r] *= corr;
    // P -> bf16 -> wave-private LDS, re-read in PV fragment layout
    us4 pk0 = { f2bf(p[0]), f2bf(p[1]), f2bf(p[2]), f2bf(p[3]) };
    us4 pk1 = { f2bf(p[4]), f2bf(p[5]), f2bf(p[6]), f2bf(p[7]) };
    *(us4*)&p_lds[wave][c15][g * 4] = pk0;
    *(us4*)&p_lds[wave][c15][16 + g * 4] = pk1;
    bf16x8 pf = *(const bf16x8*)&p_lds[wave][c15][g * 8];  // P^T B-frag
#pragma unroll
    for (int dt = 0; dt < 8; ++dt) {
      bf16x8 vf = *(const bf16x8*)&vb[(size_t)(dt * 16 + c15) * S_ + s0 + g * 8];
      ct[dt] = mfma16(vf, pf, ct[dt]);  // ctx^T[d][t]
    }
  }

  const float gsig = 1.f / (1.f + __expf(-gate[0]));
  const float inv = gsig / l_run;       // per t = c15
#pragma unroll
  for (int dt = 0; dt < 8; ++dt) {
    us4 o = { f2bf(ct[dt][0] * inv), f2bf(ct[dt][1] * inv),
              f2bf(ct[dt][2] * inv), f2bf(ct[dt][3] * inv) };
    *(us4*)&c_lds[wave][c15][dt * 16 + g * 4] = o;   // [t][d]
  }
  u16* crow = ctx + (size_t)(b * T_ + t0) * HID_ + h * HD_;
#pragma unroll
  for (int rep = 0; rep < 4; ++rep) {
    const int tt = g + rep * 4;
    us8 valv = *(const us8*)&c_lds[wave][tt][c15 * 8];
    *(us8*)&crow[(size_t)tt * HID_ + c15 * 8] = valv;
  }
}

// ---------------- launch ----------------
extern "C" void kernel_launch(void* const* d_in, const int* in_sizes, int n_in,
                              void* d_out, int out_size, void* d_ws, size_t ws_size,
                              hipStream_t stream) {
  (void)in_sizes; (void)n_in; (void)out_size; (void)ws_size;
  const float* hs   = (const float*)d_in[0];
  const float* nts  = (const float*)d_in[1];
  const int*   mask = (const int*)d_in[2];
  const float* qw   = (const float*)d_in[3];
  const float* qb   = (const float*)d_in[4];
  const float* kw   = (const float*)d_in[5];
  const float* kbi  = (const float*)d_in[6];
  const float* vw   = (const float*)d_in[7];
  const float* vbi  = (const float*)d_in[8];
  const float* ow   = (const float*)d_in[9];
  const float* obi  = (const float*)d_in[10];
  const float* gate = (const float*)d_in[11];
  float* out = (float*)d_out;

  char* w = (char*)d_ws;
  u16* h_bf   = (u16*)(w + 0);          // 33,554,432 B
  u16* n_bf   = (u16*)(w + 33554432);   //  4,194,304 B
  u16* qw_bf  = (u16*)(w + 37748736);   //  8,388,608 B
  u16* kw_bf  = (u16*)(w + 46137344);   //  4,194,304 B
  u16* vw_bf  = (u16*)(w + 50331648);   //  4,194,304 B
  u16* ow_bf  = (u16*)(w + 54525952);   //  8,388,608 B
  u16* q_bf   = (u16*)(w + 62914560);   // 33,554,432 B
  u16* k_bf   = (u16*)(w + 96468992);   //  8,388,608 B
  u16* v_bf   = (u16*)(w + 104857600);  //  8,388,608 B
  u16* vt_bf  = (u16*)(w + 113246208);  //  8,388,608 B  (end 121,634,816)
  u16* ctx_bf = h_bf;                   // alias: hidden_bf16 dead after Q-proj

  convert_all<<<dim3(2048), dim3(256), 0, stream>>>(
      hs, nts, qw, kw, vw, ow, h_bf, n_bf, qw_bf, kw_bf, vw_bf, ow_bf);
  // K,V projections: M=B*S=2048, N=HID=2048, K=ND=1024
  gemm_bt<true><<<dim3(16, 16), dim3(256), 0, stream>>>(
      n_bf, kw_bf, kbi, k_bf, 2048, 2048, 1024);
  gemm_bt<true><<<dim3(16, 16), dim3(256), 0, stream>>>(
      n_bf, vw_bf, vbi, v_bf, 2048, 2048, 1024);
  transpose_v<<<dim3(16, 64, 4), dim3(256), 0, stream>>>(v_bf, vt_bf);
  // Q projection: M=B*T=8192, N=2048, K=2048
  gemm_bt<true><<<dim3(16, 64), dim3(256), 0, stream>>>(
      h_bf, qw_bf, qb, q_bf, 8192, 2048, 2048);
  attn_fwd<<<dim3(32, 64), dim3(256), 0, stream>>>(
      q_bf, k_bf, vt_bf, mask, gate, ctx_bf);
  // Output projection -> fp32 d_out
  gemm_bt<false><<<dim3(16, 64), dim3(256), 0, stream>>>(
      ctx_bf, ow_bf, obi, out, 8192, 2048, 2048);
}

// Round 2
// 389.146 us; speedup vs baseline: 1.3710x; 1.3710x over previous
//
#include <hip/hip_runtime.h>
#include <hip/hip_bf16.h>
#include <stdint.h>

#define B_ 4
#define T_ 2048
#define S_ 512
#define HID_ 2048
#define ND_ 1024
#define NH_ 16
#define HD_ 128

typedef unsigned short u16;
typedef __attribute__((ext_vector_type(8))) short bf16x8;
typedef __attribute__((ext_vector_type(4))) float f32x4;
typedef __attribute__((ext_vector_type(4))) float f4;
typedef __attribute__((ext_vector_type(4))) u16 us4;
typedef __attribute__((ext_vector_type(8))) u16 us8;

__device__ inline u16 f2bf(float f) {
  unsigned u = __builtin_bit_cast(unsigned, f);
  u += 0x7FFFu + ((u >> 16) & 1u);   // round-to-nearest-even
  return (u16)(u >> 16);
}

__device__ inline f32x4 mfma16(bf16x8 a, bf16x8 b, f32x4 c) {
  return __builtin_amdgcn_mfma_f32_16x16x32_bf16(a, b, c, 0, 0, 0);
}

__device__ inline void gload_lds16(const u16* g, u16* l) {
  __builtin_amdgcn_global_load_lds(
      (const __attribute__((address_space(1))) unsigned int*)g,
      (__attribute__((address_space(3))) unsigned int*)l, 16, 0, 0);
}

// ---------------- fp32 -> bf16 conversion for all operands ----------------
__global__ __launch_bounds__(256) void convert_all(
    const float* __restrict__ h, const float* __restrict__ n,
    const float* __restrict__ qw, const float* __restrict__ kw,
    const float* __restrict__ vw, const float* __restrict__ ow,
    u16* __restrict__ dh, u16* __restrict__ dn, u16* __restrict__ dqw,
    u16* __restrict__ dkw, u16* __restrict__ dvw, u16* __restrict__ dow) {
  const int C0 = 4194304;            // hidden 16.78M
  const int C1 = C0 + 524288;        // notes 2.10M
  const int C2 = C1 + 1048576;       // q_w 4.19M
  const int C3 = C2 + 524288;        // k_w 2.10M
  const int C4 = C3 + 524288;        // v_w 2.10M
  const int C5 = C4 + 1048576;       // o_w 4.19M
  for (int c = blockIdx.x * blockDim.x + threadIdx.x; c < C5;
       c += gridDim.x * blockDim.x) {
    const float* s; u16* d; int o;
    if (c < C0)      { s = h;  d = dh;  o = c; }
    else if (c < C1) { s = n;  d = dn;  o = c - C0; }
    else if (c < C2) { s = qw; d = dqw; o = c - C1; }
    else if (c < C3) { s = kw; d = dkw; o = c - C2; }
    else if (c < C4) { s = vw; d = dvw; o = c - C3; }
    else             { s = ow; d = dow; o = c - C4; }
    f4 v = ((const f4*)s)[o];
    us4 r = { f2bf(v[0]), f2bf(v[1]), f2bf(v[2]), f2bf(v[3]) };
    ((us4*)d)[o] = r;
  }
}

// ---------------- GEMM: C(M,N) = A(M,K) @ B(N,K)^T + bias ----------------
template <bool OUT_BF16>
__global__ __launch_bounds__(256) void gemm_bt(
    const u16* __restrict__ A, const u16* __restrict__ Bm,
    const float* __restrict__ bias, void* __restrict__ Cout,
    int M, int N, int K) {
  __shared__ u16 As[128 * 32];
  __shared__ u16 Bs[128 * 32];
  const int tid = threadIdx.x;
  const int lane = tid & 63;
  const int wave = tid >> 6;
  const int wr = (wave >> 1) * 64;
  const int wc = (wave & 1) * 64;
  const int c15 = lane & 15;
  const int g = lane >> 4;
  const int bx = blockIdx.x, by = blockIdx.y;

  const u16* gA = A + (size_t)(by * 128 + (tid >> 2)) * K + (tid & 3) * 8;
  const u16* gB = Bm + (size_t)(bx * 128 + (tid >> 2)) * K + (tid & 3) * 8;

  f32x4 acc[4][4];
#pragma unroll
  for (int i = 0; i < 4; ++i)
#pragma unroll
    for (int j = 0; j < 4; ++j) acc[i][j] = (f32x4){0.f, 0.f, 0.f, 0.f};

  for (int k0 = 0; k0 < K; k0 += 32) {
    gload_lds16(gA + k0, &As[wave * 512]);
    gload_lds16(gA + (size_t)64 * K + k0, &As[2048 + wave * 512]);
    gload_lds16(gB + k0, &Bs[wave * 512]);
    gload_lds16(gB + (size_t)64 * K + k0, &Bs[2048 + wave * 512]);
    __syncthreads();
    bf16x8 af[4], bfr[4];
#pragma unroll
    for (int mt = 0; mt < 4; ++mt)
      af[mt] = *(const bf16x8*)&As[(wr + mt * 16 + c15) * 32 + g * 8];
#pragma unroll
    for (int nt = 0; nt < 4; ++nt)
      bfr[nt] = *(const bf16x8*)&Bs[(wc + nt * 16 + c15) * 32 + g * 8];
#pragma unroll
    for (int mt = 0; mt < 4; ++mt)
#pragma unroll
      for (int nt = 0; nt < 4; ++nt)
        acc[mt][nt] = mfma16(af[mt], bfr[nt], acc[mt][nt]);
    __syncthreads();
  }

#pragma unroll
  for (int mt = 0; mt < 4; ++mt)
#pragma unroll
    for (int nt = 0; nt < 4; ++nt) {
      const int m = by * 128 + wr + mt * 16 + g * 4;
      const int n = bx * 128 + wc + nt * 16 + c15;
      const float bv = bias[n];
#pragma unroll
      for (int r = 0; r < 4; ++r) {
        const float v = acc[mt][nt][r] + bv;
        if (OUT_BF16)
          ((u16*)Cout)[(size_t)(m + r) * N + n] = f2bf(v);
        else
          ((float*)Cout)[(size_t)(m + r) * N + n] = v;
      }
    }
}

// ---------------- V transpose: (B,S,H,D) -> (B,H,D,S) ----------------
__global__ __launch_bounds__(256) void transpose_v(const u16* __restrict__ v,
                                                   u16* __restrict__ vt) {
  __shared__ u16 tile[32][36];
  const int s0 = blockIdx.x * 32;
  const int bh = blockIdx.y;
  const int d0 = blockIdx.z * 32;
  const int b = bh >> 4, h = bh & 15;
  const int tid = threadIdx.x;
  const int sl = tid >> 3, dl = (tid & 7) * 4;
  us4 val = *(const us4*)(v + (size_t)(b * S_ + s0 + sl) * HID_ + h * HD_ + d0 + dl);
  *(us4*)&tile[sl][dl] = val;
  __syncthreads();
  const int dl2 = tid >> 3, sl2 = (tid & 7) * 4;
  us4 outv = { tile[sl2 + 0][dl2], tile[sl2 + 1][dl2],
               tile[sl2 + 2][dl2], tile[sl2 + 3][dl2] };
  *(us4*)(vt + ((size_t)bh * HD_ + d0 + dl2) * S_ + s0 + sl2) = outv;
}

// ---------------- fused masked cross-attention (flash-style) ----------------
// 4 waves/block; wave owns 16 q-rows. K/V^T staged cooperatively in LDS per
// 32-s chunk (double-buffered, global_load_lds w/ pre-swizzled source so the
// swizzled ds_reads are bank-balanced). Scores as S^T = mfma(K,Q); ctx as
// ctx^T = mfma(V^T, P^T). Defer-max online softmax (THR=8).
__global__ __launch_bounds__(256) void attn_fwd(
    const u16* __restrict__ q, const u16* __restrict__ k,
    const u16* __restrict__ vt, const int* __restrict__ mask,
    const float* __restrict__ gate, u16* __restrict__ ctx) {
  __shared__ u16 smem[16384];     // [0,8192): K bufs 2x8KB ; [8192,16384): V bufs
  __shared__ float addend[S_];
  __shared__ u16 p_lds[4][16][40];   // padded: 2-way max on bounce
  const int tid = threadIdx.x, lane = tid & 63, wave = tid >> 6;
  const int bh = blockIdx.y, b = bh >> 4, h = bh & 15;
  const int t0 = blockIdx.x * 64 + wave * 16;
  const int c15 = lane & 15, g = lane >> 4;

  const u16* kb  = k + (size_t)b * S_ * HID_ + h * HD_;
  const u16* vtb = vt + (size_t)bh * HD_ * S_;

  // ---- staging setup: waves 0,1 stage K (8x1KB), waves 2,3 stage V (8x1KB)
  // LDS dest is linear (wave-uniform base + lane*16B); the XOR swizzle is
  // applied to the per-lane GLOBAL source address (involution), so swizzled
  // reads below see logical data.
  const u16* sp[4];
  int dj[4];
  u16* ldsbase;
  ptrdiff_t stride;
  if (wave < 2) {
    ldsbase = smem;                       // K region
    stride = 32 * HID_;                   // next 32-s chunk
#pragma unroll
    for (int i = 0; i < 4; ++i) {
      const int jj = wave * 4 + i;        // 0..7
      const int row = jj * 4 + (lane >> 4);        // 0..31 (s within chunk)
      const int cb = (lane & 15) * 16;             // byte col 0..240
      const int cbp = cb ^ ((row & 7) << 4);
      sp[i] = kb + (size_t)row * HID_ + (cbp >> 1);
      dj[i] = jj * 512;
    }
  } else {
    ldsbase = smem + 8192;                // V region
    stride = 32;                          // next 32-s chunk
#pragma unroll
    for (int i = 0; i < 4; ++i) {
      const int jj = (wave - 2) * 4 + i;  // 0..7
      const int row = jj * 8 + (lane >> 3);        // 0..63 (=d>>1)
      const int cb = (lane & 7) * 16;              // byte col 0..112
      const int cbp = cb ^ ((row & 7) << 4);
      const int d = row * 2 + (cbp >> 6);
      sp[i] = vtb + (size_t)d * S_ + ((cbp & 63) >> 1);
      dj[i] = jj * 512;
    }
  }
#define STAGE(cur)                                            \
  do {                                                        \
    _Pragma("unroll") for (int i_ = 0; i_ < 4; ++i_) {        \
      gload_lds16(sp[i_], ldsbase + (cur) * 4096 + dj[i_]);   \
      sp[i_] += stride;                                       \
    }                                                         \
  } while (0)

  STAGE(0);

  for (int s = tid; s < S_; s += 256)
    addend[s] = mask[b * S_ + s] ? 0.f : -1e30f;

  // Q fragments (B-operand): col t = c15, k-dim d = dc*32 + g*8 + j
  const u16* qrow = q + (size_t)(b * T_ + t0 + c15) * HID_ + h * HD_;
  bf16x8 qf[4];
#pragma unroll
  for (int dc = 0; dc < 4; ++dc)
    qf[dc] = *(const bf16x8*)&qrow[dc * 32 + g * 8];

  // swizzled LDS read offsets (u16 units)
  const int ksw = (c15 & 7) << 4;
  int kcol[4];
#pragma unroll
  for (int dc = 0; dc < 4; ++dc)
    kcol[dc] = ((dc * 64 + g * 16) ^ ksw) >> 1;
  const int krow0 = c15 * 128, krow1 = (16 + c15) * 128;
  const int vsw = ((c15 >> 1) & 7) << 4;
  const int vcol = (((c15 & 1) * 64 + g * 16) ^ vsw) >> 1;
  const int vrow = (c15 >> 1) * 64;

  float m_run = -1e30f, l_run = 0.f;
  f32x4 ct[8];
#pragma unroll
  for (int i = 0; i < 8; ++i) ct[i] = (f32x4){0.f, 0.f, 0.f, 0.f};
  const float scale = 0.08838834764831845f;  // 1/sqrt(128)

  __syncthreads();   // buf0 staged, addend ready

  for (int it = 0; it < 16; ++it) {
    const int cur = it & 1;
    if (it < 15) STAGE(cur ^ 1);       // prefetch next chunk (other buffer)
    const int s0 = it * 32;
    const u16* kt = smem + cur * 4096;
    const u16* vl = smem + 8192 + cur * 4096;

    f32x4 st0 = {0.f, 0.f, 0.f, 0.f}, st1 = {0.f, 0.f, 0.f, 0.f};
    __builtin_amdgcn_s_setprio(1);
#pragma unroll
    for (int dc = 0; dc < 4; ++dc) {
      bf16x8 ka0 = *(const bf16x8*)&kt[krow0 + kcol[dc]];
      bf16x8 ka1 = *(const bf16x8*)&kt[krow1 + kcol[dc]];
      st0 = mfma16(ka0, qf[dc], st0);   // S^T[s][t], s = s0 + 4g + r
      st1 = mfma16(ka1, qf[dc], st1);   // s = s0 + 16 + 4g + r
    }
    __builtin_amdgcn_s_setprio(0);

    float sc[8];
#pragma unroll
    for (int r = 0; r < 4; ++r) {
      sc[r]     = st0[r] * scale + addend[s0 + g * 4 + r];
      sc[4 + r] = st1[r] * scale + addend[s0 + 16 + g * 4 + r];
    }
    float tm = sc[0];
#pragma unroll
    for (int i = 1; i < 8; ++i) tm = fmaxf(tm, sc[i]);
    tm = fmaxf(tm, __shfl_xor(tm, 16));
    tm = fmaxf(tm, __shfl_xor(tm, 32));
    const float nm = fmaxf(m_run, tm);
    if (!__all(nm - m_run <= 8.f)) {   // defer-max: rescale only when needed
      const float corr = __expf(m_run - nm);
      l_run *= corr;
#pragma unroll
      for (int dt = 0; dt < 8; ++dt)
#pragma unroll
        for (int r = 0; r < 4; ++r) ct[dt][r] *= corr;
      m_run = nm;
    }
    float p[8], ps = 0.f;
#pragma unroll
    for (int i = 0; i < 8; ++i) { p[i] = __expf(sc[i] - m_run); ps += p[i]; }
    ps += __shfl_xor(ps, 16);
    ps += __shfl_xor(ps, 32);
    l_run += ps;

    // P -> bf16 via padded LDS bounce, re-read in PV B-frag layout
    us4 pk0 = { f2bf(p[0]), f2bf(p[1]), f2bf(p[2]), f2bf(p[3]) };
    us4 pk1 = { f2bf(p[4]), f2bf(p[5]), f2bf(p[6]), f2bf(p[7]) };
    *(us4*)&p_lds[wave][c15][g * 4] = pk0;
    *(us4*)&p_lds[wave][c15][16 + g * 4] = pk1;
    bf16x8 pf = *(const bf16x8*)&p_lds[wave][c15][g * 8];

    __builtin_amdgcn_s_setprio(1);
#pragma unroll
    for (int dt = 0; dt < 8; ++dt) {
      bf16x8 vf = *(const bf16x8*)&vl[(dt * 8) * 64 + vrow + vcol];
      ct[dt] = mfma16(vf, pf, ct[dt]);  // ctx^T[d][t]
    }
    __builtin_amdgcn_s_setprio(0);

    __syncthreads();   // drains my staging vmcnt; all waves done with buf[cur]
  }
#undef STAGE

  // epilogue: transpose ctx^T -> ctx rows via padded LDS (alias dead K/V bufs)
  const float gsig = 1.f / (1.f + __expf(-gate[0]));
  const float inv = gsig / l_run;       // per t = c15
  u16* c_lds = smem + wave * (16 * 136);   // stride 136 u16 = 272B = 17*16B
#pragma unroll
  for (int dt = 0; dt < 8; ++dt) {
    us4 o = { f2bf(ct[dt][0] * inv), f2bf(ct[dt][1] * inv),
              f2bf(ct[dt][2] * inv), f2bf(ct[dt][3] * inv) };
    *(us4*)&c_lds[c15 * 136 + dt * 16 + g * 4] = o;   // [t][d]
  }
  u16* crow = ctx + (size_t)(b * T_ + t0) * HID_ + h * HD_;
#pragma unroll
  for (int rep = 0; rep < 4; ++rep) {
    const int tt = g + rep * 4;
    us8 valv = *(const us8*)&c_lds[tt * 136 + c15 * 8];
    *(us8*)&crow[(size_t)tt * HID_ + c15 * 8] = valv;
  }
}

// ---------------- launch ----------------
extern "C" void kernel_launch(void* const* d_in, const int* in_sizes, int n_in,
                              void* d_out, int out_size, void* d_ws, size_t ws_size,
                              hipStream_t stream) {
  (void)in_sizes; (void)n_in; (void)out_size; (void)ws_size;
  const float* hs   = (const float*)d_in[0];
  const float* nts  = (const float*)d_in[1];
  const int*   mask = (const int*)d_in[2];
  const float* qw   = (const float*)d_in[3];
  const float* qb   = (const float*)d_in[4];
  const float* kw   = (const float*)d_in[5];
  const float* kbi  = (const float*)d_in[6];
  const float* vw   = (const float*)d_in[7];
  const float* vbi  = (const float*)d_in[8];
  const float* ow   = (const float*)d_in[9];
  const float* obi  = (const float*)d_in[10];
  const float* gate = (const float*)d_in[11];
  float* out = (float*)d_out;

  char* w = (char*)d_ws;
  u16* h_bf   = (u16*)(w + 0);          // 33,554,432 B
  u16* n_bf   = (u16*)(w + 33554432);   //  4,194,304 B
  u16* qw_bf  = (u16*)(w + 37748736);   //  8,388,608 B
  u16* kw_bf  = (u16*)(w + 46137344);   //  4,194,304 B
  u16* vw_bf  = (u16*)(w + 50331648);   //  4,194,304 B
  u16* ow_bf  = (u16*)(w + 54525952);   //  8,388,608 B
  u16* q_bf   = (u16*)(w + 62914560);   // 33,554,432 B
  u16* k_bf   = (u16*)(w + 96468992);   //  8,388,608 B
  u16* v_bf   = (u16*)(w + 104857600);  //  8,388,608 B
  u16* vt_bf  = (u16*)(w + 113246208);  //  8,388,608 B  (end 121,634,816)
  u16* ctx_bf = h_bf;                   // alias: hidden_bf16 dead after Q-proj

  convert_all<<<dim3(2048), dim3(256), 0, stream>>>(
      hs, nts, qw, kw, vw, ow, h_bf, n_bf, qw_bf, kw_bf, vw_bf, ow_bf);
  gemm_bt<true><<<dim3(16, 16), dim3(256), 0, stream>>>(
      n_bf, kw_bf, kbi, k_bf, 2048, 2048, 1024);
  gemm_bt<true><<<dim3(16, 16), dim3(256), 0, stream>>>(
      n_bf, vw_bf, vbi, v_bf, 2048, 2048, 1024);
  transpose_v<<<dim3(16, 64, 4), dim3(256), 0, stream>>>(v_bf, vt_bf);
  gemm_bt<true><<<dim3(16, 64), dim3(256), 0, stream>>>(
      h_bf, qw_bf, qb, q_bf, 8192, 2048, 2048);
  attn_fwd<<<dim3(32, 64), dim3(256), 0, stream>>>(
      q_bf, k_bf, vt_bf, mask, gate, ctx_bf);
  gemm_bt<false><<<dim3(16, 64), dim3(256), 0, stream>>>(
      ctx_bf, ow_bf, obi, out, 8192, 2048, 2048);
}

// Round 3
// 303.064 us; speedup vs baseline: 1.7605x; 1.2840x over previous
//
#include <hip/hip_runtime.h>
#include <hip/hip_bf16.h>
#include <stdint.h>

#define B_ 4
#define T_ 2048
#define S_ 512
#define HID_ 2048
#define ND_ 1024
#define NH_ 16
#define HD_ 128

typedef unsigned short u16;
typedef __attribute__((ext_vector_type(8))) short bf16x8;
typedef __attribute__((ext_vector_type(4))) float f32x4;
typedef __attribute__((ext_vector_type(4))) float f4;
typedef __attribute__((ext_vector_type(4))) u16 us4;
typedef __attribute__((ext_vector_type(8))) u16 us8;

__device__ inline u16 f2bf(float f) {
  unsigned u = __builtin_bit_cast(unsigned, f);
  u += 0x7FFFu + ((u >> 16) & 1u);   // round-to-nearest-even
  return (u16)(u >> 16);
}

__device__ inline f32x4 mfma16(bf16x8 a, bf16x8 b, f32x4 c) {
  return __builtin_amdgcn_mfma_f32_16x16x32_bf16(a, b, c, 0, 0, 0);
}

__device__ inline void gload_lds16(const u16* g, u16* l) {
  __builtin_amdgcn_global_load_lds(
      (const __attribute__((address_space(1))) unsigned int*)g,
      (__attribute__((address_space(3))) unsigned int*)l, 16, 0, 0);
}

// ---------------- fp32 -> bf16 conversion for all operands ----------------
__global__ __launch_bounds__(256) void convert_all(
    const float* __restrict__ h, const float* __restrict__ n,
    const float* __restrict__ qw, const float* __restrict__ kw,
    const float* __restrict__ vw, const float* __restrict__ ow,
    u16* __restrict__ dh, u16* __restrict__ dn, u16* __restrict__ dqw,
    u16* __restrict__ dkw, u16* __restrict__ dvw, u16* __restrict__ dow) {
  const int C0 = 4194304;            // hidden 16.78M
  const int C1 = C0 + 524288;        // notes 2.10M
  const int C2 = C1 + 1048576;       // q_w 4.19M
  const int C3 = C2 + 524288;        // k_w 2.10M
  const int C4 = C3 + 524288;        // v_w 2.10M
  const int C5 = C4 + 1048576;       // o_w 4.19M
  for (int c = blockIdx.x * blockDim.x + threadIdx.x; c < C5;
       c += gridDim.x * blockDim.x) {
    const float* s; u16* d; int o;
    if (c < C0)      { s = h;  d = dh;  o = c; }
    else if (c < C1) { s = n;  d = dn;  o = c - C0; }
    else if (c < C2) { s = qw; d = dqw; o = c - C1; }
    else if (c < C3) { s = kw; d = dkw; o = c - C2; }
    else if (c < C4) { s = vw; d = dvw; o = c - C3; }
    else             { s = ow; d = dow; o = c - C4; }
    f4 v = ((const f4*)s)[o];
    us4 r = { f2bf(v[0]), f2bf(v[1]), f2bf(v[2]), f2bf(v[3]) };
    ((us4*)d)[o] = r;
  }
}

// ---------------- small GEMM (128^2 tile, m97 structure) ----------------
// Used for K/V projections (M=2048) where the 256^2 grid would underfill.
template <bool OUT_BF16>
__global__ __launch_bounds__(256) void gemm_bt(
    const u16* __restrict__ A, const u16* __restrict__ Bm,
    const float* __restrict__ bias, void* __restrict__ Cout,
    int M, int N, int K) {
  __shared__ u16 As[128 * 32];
  __shared__ u16 Bs[128 * 32];
  const int tid = threadIdx.x;
  const int lane = tid & 63;
  const int wave = tid >> 6;
  const int wr = (wave >> 1) * 64;
  const int wc = (wave & 1) * 64;
  const int c15 = lane & 15;
  const int g = lane >> 4;
  const int bx = blockIdx.x, by = blockIdx.y;

  const u16* gA = A + (size_t)(by * 128 + (tid >> 2)) * K + (tid & 3) * 8;
  const u16* gB = Bm + (size_t)(bx * 128 + (tid >> 2)) * K + (tid & 3) * 8;

  f32x4 acc[4][4];
#pragma unroll
  for (int i = 0; i < 4; ++i)
#pragma unroll
    for (int j = 0; j < 4; ++j) acc[i][j] = (f32x4){0.f, 0.f, 0.f, 0.f};

  for (int k0 = 0; k0 < K; k0 += 32) {
    gload_lds16(gA + k0, &As[wave * 512]);
    gload_lds16(gA + (size_t)64 * K + k0, &As[2048 + wave * 512]);
    gload_lds16(gB + k0, &Bs[wave * 512]);
    gload_lds16(gB + (size_t)64 * K + k0, &Bs[2048 + wave * 512]);
    __syncthreads();
    bf16x8 af[4], bfr[4];
#pragma unroll
    for (int mt = 0; mt < 4; ++mt)
      af[mt] = *(const bf16x8*)&As[(wr + mt * 16 + c15) * 32 + g * 8];
#pragma unroll
    for (int nt = 0; nt < 4; ++nt)
      bfr[nt] = *(const bf16x8*)&Bs[(wc + nt * 16 + c15) * 32 + g * 8];
#pragma unroll
    for (int mt = 0; mt < 4; ++mt)
#pragma unroll
      for (int nt = 0; nt < 4; ++nt)
        acc[mt][nt] = mfma16(af[mt], bfr[nt], acc[mt][nt]);
    __syncthreads();
  }

#pragma unroll
  for (int mt = 0; mt < 4; ++mt)
#pragma unroll
    for (int nt = 0; nt < 4; ++nt) {
      const int m = by * 128 + wr + mt * 16 + g * 4;
      const int n = bx * 128 + wc + nt * 16 + c15;
      const float bv = bias[n];
#pragma unroll
      for (int r = 0; r < 4; ++r) {
        const float v = acc[mt][nt][r] + bv;
        if (OUT_BF16)
          ((u16*)Cout)[(size_t)(m + r) * N + n] = f2bf(v);
        else
          ((float*)Cout)[(size_t)(m + r) * N + n] = v;
      }
    }
}

// ------------- big GEMM: 256^2 tile, multi-phase counted-vmcnt -------------
// 8 waves (2M x 4N), BK=32, 3 rotating LDS buffers (96 KB). Per K-tile:
// 2 phases of {ds_read subtile; 2 x global_load_lds for tile t+2; s_barrier;
// setprio(1); 16 MFMA; setprio(0); s_barrier}. Boundary wait = vmcnt(4)
// (retires exactly tile t+1's 4 loads; in-order retirement), vmcnt(0) only
// at the last boundary. T2 swizzle: chunk' = chunk ^ ((row>>1)&3), applied
// to pre-swizzled global source AND ds_read address (both-sides involution).
template <bool OUT_BF16>
__global__ __launch_bounds__(512, 2) void gemm256(
    const u16* __restrict__ A, const u16* __restrict__ Bm,
    const float* __restrict__ bias, void* __restrict__ Cout,
    int M, int N, int K) {
  extern __shared__ u16 lds[];          // 3 bufs x (A 8192 + B 8192) u16
  const int tid = threadIdx.x;
  const int lane = tid & 63, wave = tid >> 6;
  const int wm = wave >> 2, wn = wave & 3;
  const int c15 = lane & 15, g = lane >> 4;
  const int bn = blockIdx.x, bm = blockIdx.y;
  const int NT = K >> 5;

  // staging: thread -> (row = i*128 + tid>>2, chunk = tid&3), source chunk
  // pre-swizzled so linear LDS dest + swizzled read = logical data.
  const int srow = tid >> 2;
  const int sx = (tid & 3) ^ ((srow >> 1) & 3);
  const u16* pa0 = A + (size_t)(bm * 256 + srow) * K + sx * 8;
  const u16* pa1 = A + (size_t)(bm * 256 + 128 + srow) * K + sx * 8;
  const u16* pb0 = Bm + (size_t)(bn * 256 + srow) * K + sx * 8;
  const u16* pb1 = Bm + (size_t)(bn * 256 + 128 + srow) * K + sx * 8;

  // ds_read offsets (u16 units), swizzled chunk = g ^ ((row>>1)&3)
  const int xr = (c15 >> 1) & 3;
  const int aoff = wm * 4096 + c15 * 32 + ((g ^ xr)) * 8;
  const int boff = 8192 + wn * 2048 + c15 * 32 + ((g ^ xr)) * 8;

  f32x4 acc[8][4];
#pragma unroll
  for (int i = 0; i < 8; ++i)
#pragma unroll
    for (int j = 0; j < 4; ++j) acc[i][j] = (f32x4){0.f, 0.f, 0.f, 0.f};

  // prologue: stage tiles 0 (buf0) and 1 (buf1); wait tile 0 (oldest 4)
  {
    u16* sA = lds + wave * 512;
    u16* sB = lds + 8192 + wave * 512;
    gload_lds16(pa0, sA);          gload_lds16(pa1, sA + 4096);
    gload_lds16(pb0, sB);          gload_lds16(pb1, sB + 4096);
    pa0 += 32; pa1 += 32; pb0 += 32; pb1 += 32;
    gload_lds16(pa0, sA + 16384);  gload_lds16(pa1, sA + 20480);
    gload_lds16(pb0, sB + 16384);  gload_lds16(pb1, sB + 20480);
    pa0 += 32; pa1 += 32; pb0 += 32; pb1 += 32;
  }
  asm volatile("s_waitcnt vmcnt(4)" ::: "memory");
  __builtin_amdgcn_s_barrier();
  __builtin_amdgcn_sched_barrier(0);

  int curo = 0, stgo = 32768;
  for (int t = 0; t < NT; ++t) {
    const bool more = (t + 2 < NT);
    const u16* cb = lds + curo;
    // ---- phase A: a0..a3 + b0..b3, stage A-halves of tile t+2
    bf16x8 a[4], b[4];
#pragma unroll
    for (int mf = 0; mf < 4; ++mf)
      a[mf] = *(const bf16x8*)(cb + aoff + mf * 512);
#pragma unroll
    for (int nf = 0; nf < 4; ++nf)
      b[nf] = *(const bf16x8*)(cb + boff + nf * 512);
    if (more) {
      gload_lds16(pa0, lds + stgo + wave * 512);
      gload_lds16(pa1, lds + stgo + 4096 + wave * 512);
    }
    __builtin_amdgcn_s_barrier();
    __builtin_amdgcn_sched_barrier(0);
    __builtin_amdgcn_s_setprio(1);
#pragma unroll
    for (int mf = 0; mf < 4; ++mf)
#pragma unroll
      for (int nf = 0; nf < 4; ++nf)
        acc[mf][nf] = mfma16(a[mf], b[nf], acc[mf][nf]);
    __builtin_amdgcn_s_setprio(0);
    __builtin_amdgcn_s_barrier();
    __builtin_amdgcn_sched_barrier(0);
    // ---- phase B: a4..a7 (b held), stage B-halves of tile t+2
    bf16x8 a2[4];
#pragma unroll
    for (int mf = 0; mf < 4; ++mf)
      a2[mf] = *(const bf16x8*)(cb + aoff + (4 + mf) * 512);
    if (more) {
      gload_lds16(pb0, lds + stgo + 8192 + wave * 512);
      gload_lds16(pb1, lds + stgo + 12288 + wave * 512);
      pa0 += 32; pa1 += 32; pb0 += 32; pb1 += 32;
    }
    __builtin_amdgcn_s_barrier();
    __builtin_amdgcn_sched_barrier(0);
    __builtin_amdgcn_s_setprio(1);
#pragma unroll
    for (int mf = 0; mf < 4; ++mf)
#pragma unroll
      for (int nf = 0; nf < 4; ++nf)
        acc[4 + mf][nf] = mfma16(a2[mf], b[nf], acc[4 + mf][nf]);
    __builtin_amdgcn_s_setprio(0);
    if (t < NT - 1) {
      if (more) asm volatile("s_waitcnt vmcnt(4)" ::: "memory");
      else      asm volatile("s_waitcnt vmcnt(0)" ::: "memory");
    }
    __builtin_amdgcn_s_barrier();
    __builtin_amdgcn_sched_barrier(0);
    curo = (curo == 32768) ? 0 : curo + 16384;
    stgo = (stgo == 32768) ? 0 : stgo + 16384;
  }

  // epilogue: bias + store (C row = g*4+r, col = c15 per fragment)
#pragma unroll
  for (int mf = 0; mf < 8; ++mf)
#pragma unroll
    for (int nf = 0; nf < 4; ++nf) {
      const int m = bm * 256 + wm * 128 + mf * 16 + g * 4;
      const int n = bn * 256 + wn * 64 + nf * 16 + c15;
      const float bv = bias[n];
#pragma unroll
      for (int r = 0; r < 4; ++r) {
        const float v = acc[mf][nf][r] + bv;
        if (OUT_BF16)
          ((u16*)Cout)[(size_t)(m + r) * N + n] = f2bf(v);
        else
          ((float*)Cout)[(size_t)(m + r) * N + n] = v;
      }
    }
}

// ---------------- V transpose: (B,S,H,D) -> (B,H,D,S) ----------------
__global__ __launch_bounds__(256) void transpose_v(const u16* __restrict__ v,
                                                   u16* __restrict__ vt) {
  __shared__ u16 tile[32][36];
  const int s0 = blockIdx.x * 32;
  const int bh = blockIdx.y;
  const int d0 = blockIdx.z * 32;
  const int b = bh >> 4, h = bh & 15;
  const int tid = threadIdx.x;
  const int sl = tid >> 3, dl = (tid & 7) * 4;
  us4 val = *(const us4*)(v + (size_t)(b * S_ + s0 + sl) * HID_ + h * HD_ + d0 + dl);
  *(us4*)&tile[sl][dl] = val;
  __syncthreads();
  const int dl2 = tid >> 3, sl2 = (tid & 7) * 4;
  us4 outv = { tile[sl2 + 0][dl2], tile[sl2 + 1][dl2],
               tile[sl2 + 2][dl2], tile[sl2 + 3][dl2] };
  *(us4*)(vt + ((size_t)bh * HD_ + d0 + dl2) * S_ + s0 + sl2) = outv;
}

// ---------------- fused masked cross-attention (flash-style) ----------------
__global__ __launch_bounds__(256) void attn_fwd(
    const u16* __restrict__ q, const u16* __restrict__ k,
    const u16* __restrict__ vt, const int* __restrict__ mask,
    const float* __restrict__ gate, u16* __restrict__ ctx) {
  __shared__ u16 smem[16384];     // [0,8192): K bufs 2x8KB ; [8192,16384): V bufs
  __shared__ float addend[S_];
  __shared__ u16 p_lds[4][16][40];   // padded: 2-way max on bounce
  const int tid = threadIdx.x, lane = tid & 63, wave = tid >> 6;
  const int bh = blockIdx.y, b = bh >> 4, h = bh & 15;
  const int t0 = blockIdx.x * 64 + wave * 16;
  const int c15 = lane & 15, g = lane >> 4;

  const u16* kb  = k + (size_t)b * S_ * HID_ + h * HD_;
  const u16* vtb = vt + (size_t)bh * HD_ * S_;

  const u16* sp[4];
  int dj[4];
  u16* ldsbase;
  ptrdiff_t stride;
  if (wave < 2) {
    ldsbase = smem;                       // K region
    stride = 32 * HID_;
#pragma unroll
    for (int i = 0; i < 4; ++i) {
      const int jj = wave * 4 + i;
      const int row = jj * 4 + (lane >> 4);
      const int cb = (lane & 15) * 16;
      const int cbp = cb ^ ((row & 7) << 4);
      sp[i] = kb + (size_t)row * HID_ + (cbp >> 1);
      dj[i] = jj * 512;
    }
  } else {
    ldsbase = smem + 8192;                // V region
    stride = 32;
#pragma unroll
    for (int i = 0; i < 4; ++i) {
      const int jj = (wave - 2) * 4 + i;
      const int row = jj * 8 + (lane >> 3);
      const int cb = (lane & 7) * 16;
      const int cbp = cb ^ ((row & 7) << 4);
      const int d = row * 2 + (cbp >> 6);
      sp[i] = vtb + (size_t)d * S_ + ((cbp & 63) >> 1);
      dj[i] = jj * 512;
    }
  }
#define STAGE(cur)                                            \
  do {                                                        \
    _Pragma("unroll") for (int i_ = 0; i_ < 4; ++i_) {        \
      gload_lds16(sp[i_], ldsbase + (cur) * 4096 + dj[i_]);   \
      sp[i_] += stride;                                       \
    }                                                         \
  } while (0)

  STAGE(0);

  for (int s = tid; s < S_; s += 256)
    addend[s] = mask[b * S_ + s] ? 0.f : -1e30f;

  const u16* qrow = q + (size_t)(b * T_ + t0 + c15) * HID_ + h * HD_;
  bf16x8 qf[4];
#pragma unroll
  for (int dc = 0; dc < 4; ++dc)
    qf[dc] = *(const bf16x8*)&qrow[dc * 32 + g * 8];

  const int ksw = (c15 & 7) << 4;
  int kcol[4];
#pragma unroll
  for (int dc = 0; dc < 4; ++dc)
    kcol[dc] = ((dc * 64 + g * 16) ^ ksw) >> 1;
  const int krow0 = c15 * 128, krow1 = (16 + c15) * 128;
  const int vsw = ((c15 >> 1) & 7) << 4;
  const int vcol = (((c15 & 1) * 64 + g * 16) ^ vsw) >> 1;
  const int vrow = (c15 >> 1) * 64;

  float m_run = -1e30f, l_run = 0.f;
  f32x4 ct[8];
#pragma unroll
  for (int i = 0; i < 8; ++i) ct[i] = (f32x4){0.f, 0.f, 0.f, 0.f};
  const float scale = 0.08838834764831845f;  // 1/sqrt(128)

  __syncthreads();   // buf0 staged, addend ready

  for (int it = 0; it < 16; ++it) {
    const int cur = it & 1;
    if (it < 15) STAGE(cur ^ 1);
    const int s0 = it * 32;
    const u16* kt = smem + cur * 4096;
    const u16* vl = smem + 8192 + cur * 4096;

    f32x4 st0 = {0.f, 0.f, 0.f, 0.f}, st1 = {0.f, 0.f, 0.f, 0.f};
    __builtin_amdgcn_s_setprio(1);
#pragma unroll
    for (int dc = 0; dc < 4; ++dc) {
      bf16x8 ka0 = *(const bf16x8*)&kt[krow0 + kcol[dc]];
      bf16x8 ka1 = *(const bf16x8*)&kt[krow1 + kcol[dc]];
      st0 = mfma16(ka0, qf[dc], st0);
      st1 = mfma16(ka1, qf[dc], st1);
    }
    __builtin_amdgcn_s_setprio(0);

    float sc[8];
#pragma unroll
    for (int r = 0; r < 4; ++r) {
      sc[r]     = st0[r] * scale + addend[s0 + g * 4 + r];
      sc[4 + r] = st1[r] * scale + addend[s0 + 16 + g * 4 + r];
    }
    float tm = sc[0];
#pragma unroll
    for (int i = 1; i < 8; ++i) tm = fmaxf(tm, sc[i]);
    tm = fmaxf(tm, __shfl_xor(tm, 16));
    tm = fmaxf(tm, __shfl_xor(tm, 32));
    const float nm = fmaxf(m_run, tm);
    if (!__all(nm - m_run <= 8.f)) {
      const float corr = __expf(m_run - nm);
      l_run *= corr;
#pragma unroll
      for (int dt = 0; dt < 8; ++dt)
#pragma unroll
        for (int r = 0; r < 4; ++r) ct[dt][r] *= corr;
      m_run = nm;
    }
    float p[8], ps = 0.f;
#pragma unroll
    for (int i = 0; i < 8; ++i) { p[i] = __expf(sc[i] - m_run); ps += p[i]; }
    ps += __shfl_xor(ps, 16);
    ps += __shfl_xor(ps, 32);
    l_run += ps;

    us4 pk0 = { f2bf(p[0]), f2bf(p[1]), f2bf(p[2]), f2bf(p[3]) };
    us4 pk1 = { f2bf(p[4]), f2bf(p[5]), f2bf(p[6]), f2bf(p[7]) };
    *(us4*)&p_lds[wave][c15][g * 4] = pk0;
    *(us4*)&p_lds[wave][c15][16 + g * 4] = pk1;
    bf16x8 pf = *(const bf16x8*)&p_lds[wave][c15][g * 8];

    __builtin_amdgcn_s_setprio(1);
#pragma unroll
    for (int dt = 0; dt < 8; ++dt) {
      bf16x8 vf = *(const bf16x8*)&vl[(dt * 8) * 64 + vrow + vcol];
      ct[dt] = mfma16(vf, pf, ct[dt]);
    }
    __builtin_amdgcn_s_setprio(0);

    __syncthreads();
  }
#undef STAGE

  const float gsig = 1.f / (1.f + __expf(-gate[0]));
  const float inv = gsig / l_run;
  u16* c_lds = smem + wave * (16 * 136);
#pragma unroll
  for (int dt = 0; dt < 8; ++dt) {
    us4 o = { f2bf(ct[dt][0] * inv), f2bf(ct[dt][1] * inv),
              f2bf(ct[dt][2] * inv), f2bf(ct[dt][3] * inv) };
    *(us4*)&c_lds[c15 * 136 + dt * 16 + g * 4] = o;
  }
  u16* crow = ctx + (size_t)(b * T_ + t0) * HID_ + h * HD_;
#pragma unroll
  for (int rep = 0; rep < 4; ++rep) {
    const int tt = g + rep * 4;
    us8 valv = *(const us8*)&c_lds[tt * 136 + c15 * 8];
    *(us8*)&crow[(size_t)tt * HID_ + c15 * 8] = valv;
  }
}

// ---------------- launch ----------------
extern "C" void kernel_launch(void* const* d_in, const int* in_sizes, int n_in,
                              void* d_out, int out_size, void* d_ws, size_t ws_size,
                              hipStream_t stream) {
  (void)in_sizes; (void)n_in; (void)out_size; (void)ws_size;
  const float* hs   = (const float*)d_in[0];
  const float* nts  = (const float*)d_in[1];
  const int*   mask = (const int*)d_in[2];
  const float* qw   = (const float*)d_in[3];
  const float* qb   = (const float*)d_in[4];
  const float* kw   = (const float*)d_in[5];
  const float* kbi  = (const float*)d_in[6];
  const float* vw   = (const float*)d_in[7];
  const float* vbi  = (const float*)d_in[8];
  const float* ow   = (const float*)d_in[9];
  const float* obi  = (const float*)d_in[10];
  const float* gate = (const float*)d_in[11];
  float* out = (float*)d_out;

  char* w = (char*)d_ws;
  u16* h_bf   = (u16*)(w + 0);          // 33,554,432 B
  u16* n_bf   = (u16*)(w + 33554432);   //  4,194,304 B
  u16* qw_bf  = (u16*)(w + 37748736);   //  8,388,608 B
  u16* kw_bf  = (u16*)(w + 46137344);   //  4,194,304 B
  u16* vw_bf  = (u16*)(w + 50331648);   //  4,194,304 B
  u16* ow_bf  = (u16*)(w + 54525952);   //  8,388,608 B
  u16* q_bf   = (u16*)(w + 62914560);   // 33,554,432 B
  u16* k_bf   = (u16*)(w + 96468992);   //  8,388,608 B
  u16* v_bf   = (u16*)(w + 104857600);  //  8,388,608 B
  u16* vt_bf  = (u16*)(w + 113246208);  //  8,388,608 B  (end 121,634,816)
  u16* ctx_bf = h_bf;                   // alias: hidden_bf16 dead after Q-proj

  // opt-in to 96 KB dynamic LDS for the 256^2 kernel (host-side, capture-safe)
  hipFuncSetAttribute(reinterpret_cast<const void*>(&gemm256<true>),
                      hipFuncAttributeMaxDynamicSharedMemorySize, 98304);
  hipFuncSetAttribute(reinterpret_cast<const void*>(&gemm256<false>),
                      hipFuncAttributeMaxDynamicSharedMemorySize, 98304);

  convert_all<<<dim3(2048), dim3(256), 0, stream>>>(
      hs, nts, qw, kw, vw, ow, h_bf, n_bf, qw_bf, kw_bf, vw_bf, ow_bf);
  gemm_bt<true><<<dim3(16, 16), dim3(256), 0, stream>>>(
      n_bf, kw_bf, kbi, k_bf, 2048, 2048, 1024);
  gemm_bt<true><<<dim3(16, 16), dim3(256), 0, stream>>>(
      n_bf, vw_bf, vbi, v_bf, 2048, 2048, 1024);
  transpose_v<<<dim3(16, 64, 4), dim3(256), 0, stream>>>(v_bf, vt_bf);
  // Q projection: M=8192, N=2048, K=2048 — 256^2 pipeline, grid 8x32 = 256 CUs
  gemm256<true><<<dim3(8, 32), dim3(512), 98304, stream>>>(
      h_bf, qw_bf, qb, q_bf, 8192, 2048, 2048);
  attn_fwd<<<dim3(32, 64), dim3(256), 0, stream>>>(
      q_bf, k_bf, vt_bf, mask, gate, ctx_bf);
  // Output projection -> fp32 d_out
  gemm256<false><<<dim3(8, 32), dim3(512), 98304, stream>>>(
      ctx_bf, ow_bf, obi, out, 8192, 2048, 2048);
}

// Round 4
// 285.677 us; speedup vs baseline: 1.8676x; 1.0609x over previous
//
#include <hip/hip_runtime.h>
#include <hip/hip_bf16.h>
#include <stdint.h>

#define B_ 4
#define T_ 2048
#define S_ 512
#define HID_ 2048
#define ND_ 1024
#define NH_ 16
#define HD_ 128

typedef unsigned short u16;
typedef unsigned int u32;
typedef __attribute__((ext_vector_type(8))) short bf16x8;
typedef __attribute__((ext_vector_type(4))) float f32x4;
typedef __attribute__((ext_vector_type(16))) float f32x16;
typedef __attribute__((ext_vector_type(4))) float f4;
typedef __attribute__((ext_vector_type(4))) u16 us4;
typedef __attribute__((ext_vector_type(8))) u16 us8;
typedef __attribute__((ext_vector_type(4))) u32 u32x4;

__device__ inline u16 f2bf(float f) {
  unsigned u = __builtin_bit_cast(unsigned, f);
  u += 0x7FFFu + ((u >> 16) & 1u);   // round-to-nearest-even
  return (u16)(u >> 16);
}

__device__ inline u32 cvtpk(float lo, float hi) {   // bf16(lo) | bf16(hi)<<16
  u32 r;
  asm("v_cvt_pk_bf16_f32 %0, %1, %2" : "=v"(r) : "v"(lo), "v"(hi));
  return r;
}

__device__ inline f32x4 mfma16(bf16x8 a, bf16x8 b, f32x4 c) {
  return __builtin_amdgcn_mfma_f32_16x16x32_bf16(a, b, c, 0, 0, 0);
}
__device__ inline f32x16 mfma32(bf16x8 a, bf16x8 b, f32x16 c) {
  return __builtin_amdgcn_mfma_f32_32x32x16_bf16(a, b, c, 0, 0, 0);
}

__device__ inline void gload_lds16(const u16* g, u16* l) {
  __builtin_amdgcn_global_load_lds(
      (const __attribute__((address_space(1))) unsigned int*)g,
      (__attribute__((address_space(3))) unsigned int*)l, 16, 0, 0);
}

// ---------------- fp32 -> bf16 conversion for all operands ----------------
__global__ __launch_bounds__(256) void convert_all(
    const float* __restrict__ h, const float* __restrict__ n,
    const float* __restrict__ qw, const float* __restrict__ kw,
    const float* __restrict__ vw, const float* __restrict__ ow,
    u16* __restrict__ dh, u16* __restrict__ dn, u16* __restrict__ dqw,
    u16* __restrict__ dkw, u16* __restrict__ dvw, u16* __restrict__ dow) {
  const int C0 = 4194304;            // hidden 16.78M
  const int C1 = C0 + 524288;        // notes 2.10M
  const int C2 = C1 + 1048576;       // q_w 4.19M
  const int C3 = C2 + 524288;        // k_w 2.10M
  const int C4 = C3 + 524288;        // v_w 2.10M
  const int C5 = C4 + 1048576;       // o_w 4.19M
  for (int c = blockIdx.x * blockDim.x + threadIdx.x; c < C5;
       c += gridDim.x * blockDim.x) {
    const float* s; u16* d; int o;
    if (c < C0)      { s = h;  d = dh;  o = c; }
    else if (c < C1) { s = n;  d = dn;  o = c - C0; }
    else if (c < C2) { s = qw; d = dqw; o = c - C1; }
    else if (c < C3) { s = kw; d = dkw; o = c - C2; }
    else if (c < C4) { s = vw; d = dvw; o = c - C3; }
    else             { s = ow; d = dow; o = c - C4; }
    f4 v = ((const f4*)s)[o];
    us4 r = { f2bf(v[0]), f2bf(v[1]), f2bf(v[2]), f2bf(v[3]) };
    ((us4*)d)[o] = r;
  }
}

// ---------------- small GEMM (128^2 tile, m97 structure) ----------------
template <bool OUT_BF16>
__global__ __launch_bounds__(256) void gemm_bt(
    const u16* __restrict__ A, const u16* __restrict__ Bm,
    const float* __restrict__ bias, void* __restrict__ Cout,
    int M, int N, int K) {
  __shared__ u16 As[128 * 32];
  __shared__ u16 Bs[128 * 32];
  const int tid = threadIdx.x;
  const int lane = tid & 63;
  const int wave = tid >> 6;
  const int wr = (wave >> 1) * 64;
  const int wc = (wave & 1) * 64;
  const int c15 = lane & 15;
  const int g = lane >> 4;
  const int bx = blockIdx.x, by = blockIdx.y;

  const u16* gA = A + (size_t)(by * 128 + (tid >> 2)) * K + (tid & 3) * 8;
  const u16* gB = Bm + (size_t)(bx * 128 + (tid >> 2)) * K + (tid & 3) * 8;

  f32x4 acc[4][4];
#pragma unroll
  for (int i = 0; i < 4; ++i)
#pragma unroll
    for (int j = 0; j < 4; ++j) acc[i][j] = (f32x4){0.f, 0.f, 0.f, 0.f};

  for (int k0 = 0; k0 < K; k0 += 32) {
    gload_lds16(gA + k0, &As[wave * 512]);
    gload_lds16(gA + (size_t)64 * K + k0, &As[2048 + wave * 512]);
    gload_lds16(gB + k0, &Bs[wave * 512]);
    gload_lds16(gB + (size_t)64 * K + k0, &Bs[2048 + wave * 512]);
    __syncthreads();
    bf16x8 af[4], bfr[4];
#pragma unroll
    for (int mt = 0; mt < 4; ++mt)
      af[mt] = *(const bf16x8*)&As[(wr + mt * 16 + c15) * 32 + g * 8];
#pragma unroll
    for (int nt = 0; nt < 4; ++nt)
      bfr[nt] = *(const bf16x8*)&Bs[(wc + nt * 16 + c15) * 32 + g * 8];
#pragma unroll
    for (int mt = 0; mt < 4; ++mt)
#pragma unroll
      for (int nt = 0; nt < 4; ++nt)
        acc[mt][nt] = mfma16(af[mt], bfr[nt], acc[mt][nt]);
    __syncthreads();
  }

#pragma unroll
  for (int mt = 0; mt < 4; ++mt)
#pragma unroll
    for (int nt = 0; nt < 4; ++nt) {
      const int m = by * 128 + wr + mt * 16 + g * 4;
      const int n = bx * 128 + wc + nt * 16 + c15;
      const float bv = bias[n];
#pragma unroll
      for (int r = 0; r < 4; ++r) {
        const float v = acc[mt][nt][r] + bv;
        if (OUT_BF16)
          ((u16*)Cout)[(size_t)(m + r) * N + n] = f2bf(v);
        else
          ((float*)Cout)[(size_t)(m + r) * N + n] = v;
      }
    }
}

// ------------- big GEMM: 256^2 tile, multi-phase counted-vmcnt -------------
// (structure unchanged from round 3; added bijective XCD-contiguous block
// swizzle: 256 blocks, XCD x gets 32 consecutive logical ids = 4 bm-panels)
template <bool OUT_BF16>
__global__ __launch_bounds__(512, 2) void gemm256(
    const u16* __restrict__ A, const u16* __restrict__ Bm,
    const float* __restrict__ bias, void* __restrict__ Cout,
    int M, int N, int K) {
  extern __shared__ u16 lds[];          // 3 bufs x (A 8192 + B 8192) u16
  const int tid = threadIdx.x;
  const int lane = tid & 63, wave = tid >> 6;
  const int wm = wave >> 2, wn = wave & 3;
  const int c15 = lane & 15, g = lane >> 4;
  const int bid = blockIdx.y * gridDim.x + blockIdx.x;
  const int sw = (bid & 7) * 32 + (bid >> 3);   // XCD-contiguous, bijective
  const int bn = sw & 7, bm = sw >> 3;
  const int NT = K >> 5;

  const int srow = tid >> 2;
  const int sx = (tid & 3) ^ ((srow >> 1) & 3);
  const u16* pa0 = A + (size_t)(bm * 256 + srow) * K + sx * 8;
  const u16* pa1 = A + (size_t)(bm * 256 + 128 + srow) * K + sx * 8;
  const u16* pb0 = Bm + (size_t)(bn * 256 + srow) * K + sx * 8;
  const u16* pb1 = Bm + (size_t)(bn * 256 + 128 + srow) * K + sx * 8;

  const int xr = (c15 >> 1) & 3;
  const int aoff = wm * 4096 + c15 * 32 + ((g ^ xr)) * 8;
  const int boff = 8192 + wn * 2048 + c15 * 32 + ((g ^ xr)) * 8;

  f32x4 acc[8][4];
#pragma unroll
  for (int i = 0; i < 8; ++i)
#pragma unroll
    for (int j = 0; j < 4; ++j) acc[i][j] = (f32x4){0.f, 0.f, 0.f, 0.f};

  {
    u16* sA = lds + wave * 512;
    u16* sB = lds + 8192 + wave * 512;
    gload_lds16(pa0, sA);          gload_lds16(pa1, sA + 4096);
    gload_lds16(pb0, sB);          gload_lds16(pb1, sB + 4096);
    pa0 += 32; pa1 += 32; pb0 += 32; pb1 += 32;
    gload_lds16(pa0, sA + 16384);  gload_lds16(pa1, sA + 20480);
    gload_lds16(pb0, sB + 16384);  gload_lds16(pb1, sB + 20480);
    pa0 += 32; pa1 += 32; pb0 += 32; pb1 += 32;
  }
  asm volatile("s_waitcnt vmcnt(4)" ::: "memory");
  __builtin_amdgcn_s_barrier();
  __builtin_amdgcn_sched_barrier(0);

  int curo = 0, stgo = 32768;
  for (int t = 0; t < NT; ++t) {
    const bool more = (t + 2 < NT);
    const u16* cb = lds + curo;
    bf16x8 a[4], b[4];
#pragma unroll
    for (int mf = 0; mf < 4; ++mf)
      a[mf] = *(const bf16x8*)(cb + aoff + mf * 512);
#pragma unroll
    for (int nf = 0; nf < 4; ++nf)
      b[nf] = *(const bf16x8*)(cb + boff + nf * 512);
    if (more) {
      gload_lds16(pa0, lds + stgo + wave * 512);
      gload_lds16(pa1, lds + stgo + 4096 + wave * 512);
    }
    __builtin_amdgcn_s_barrier();
    __builtin_amdgcn_sched_barrier(0);
    __builtin_amdgcn_s_setprio(1);
#pragma unroll
    for (int mf = 0; mf < 4; ++mf)
#pragma unroll
      for (int nf = 0; nf < 4; ++nf)
        acc[mf][nf] = mfma16(a[mf], b[nf], acc[mf][nf]);
    __builtin_amdgcn_s_setprio(0);
    __builtin_amdgcn_s_barrier();
    __builtin_amdgcn_sched_barrier(0);
    bf16x8 a2[4];
#pragma unroll
    for (int mf = 0; mf < 4; ++mf)
      a2[mf] = *(const bf16x8*)(cb + aoff + (4 + mf) * 512);
    if (more) {
      gload_lds16(pb0, lds + stgo + 8192 + wave * 512);
      gload_lds16(pb1, lds + stgo + 12288 + wave * 512);
      pa0 += 32; pa1 += 32; pb0 += 32; pb1 += 32;
    }
    __builtin_amdgcn_s_barrier();
    __builtin_amdgcn_sched_barrier(0);
    __builtin_amdgcn_s_setprio(1);
#pragma unroll
    for (int mf = 0; mf < 4; ++mf)
#pragma unroll
      for (int nf = 0; nf < 4; ++nf)
        acc[4 + mf][nf] = mfma16(a2[mf], b[nf], acc[4 + mf][nf]);
    __builtin_amdgcn_s_setprio(0);
    if (t < NT - 1) {
      if (more) asm volatile("s_waitcnt vmcnt(4)" ::: "memory");
      else      asm volatile("s_waitcnt vmcnt(0)" ::: "memory");
    }
    __builtin_amdgcn_s_barrier();
    __builtin_amdgcn_sched_barrier(0);
    curo = (curo == 32768) ? 0 : curo + 16384;
    stgo = (stgo == 32768) ? 0 : stgo + 16384;
  }

#pragma unroll
  for (int mf = 0; mf < 8; ++mf)
#pragma unroll
    for (int nf = 0; nf < 4; ++nf) {
      const int m = bm * 256 + wm * 128 + mf * 16 + g * 4;
      const int n = bn * 256 + wn * 64 + nf * 16 + c15;
      const float bv = bias[n];
#pragma unroll
      for (int r = 0; r < 4; ++r) {
        const float v = acc[mf][nf][r] + bv;
        if (OUT_BF16)
          ((u16*)Cout)[(size_t)(m + r) * N + n] = f2bf(v);
        else
          ((float*)Cout)[(size_t)(m + r) * N + n] = v;
      }
    }
}

// ---------------- V transpose: (B,S,H,D) -> (B,H,D,S) ----------------
__global__ __launch_bounds__(256) void transpose_v(const u16* __restrict__ v,
                                                   u16* __restrict__ vt) {
  __shared__ u16 tile[32][36];
  const int s0 = blockIdx.x * 32;
  const int bh = blockIdx.y;
  const int d0 = blockIdx.z * 32;
  const int b = bh >> 4, h = bh & 15;
  const int tid = threadIdx.x;
  const int sl = tid >> 3, dl = (tid & 7) * 4;
  us4 val = *(const us4*)(v + (size_t)(b * S_ + s0 + sl) * HID_ + h * HD_ + d0 + dl);
  *(us4*)&tile[sl][dl] = val;
  __syncthreads();
  const int dl2 = tid >> 3, sl2 = (tid & 7) * 4;
  us4 outv = { tile[sl2 + 0][dl2], tile[sl2 + 1][dl2],
               tile[sl2 + 2][dl2], tile[sl2 + 3][dl2] };
  *(us4*)(vt + ((size_t)bh * HD_ + d0 + dl2) * S_ + s0 + sl2) = outv;
}

// ---------------- fused masked cross-attention, 32x32 MFMA ----------------
// 4 waves/block; wave owns 32 q-rows (t = lane&31, hi = lane>>5 gives the two
// s-halves). S^T = mfma32(K, Q): lane holds 16 s-values for its t. P packed
// in-register (cvt_pk + shfl_xor(32)) directly into the PV B-fragment; ctx^T
// = mfma32(V^T, P^T). K/V staged double-buffered via swizzled-source
// global_load_lds; K row swizzle (s&7)<<4 (256B rows), V (d&3)<<4 (64B rows).
__global__ __launch_bounds__(256) void attn_fwd(
    const u16* __restrict__ q, const u16* __restrict__ k,
    const u16* __restrict__ vt, const int* __restrict__ mask,
    const float* __restrict__ gate, u16* __restrict__ ctx) {
  __shared__ u16 smem[17408];   // [0,8192) K bufs x2; [8192,16384) V bufs x2;
                                // epilogue reuses [0,17408) as 4x stride-136
  __shared__ float addend[S_];
  const int tid = threadIdx.x, lane = tid & 63, wave = tid >> 6;
  const int bh = blockIdx.y, b = bh >> 4, h = bh & 15;
  const int tw = blockIdx.x * 128 + wave * 32;
  const int l31 = lane & 31, hi = lane >> 5;

  const u16* kb  = k + (size_t)b * S_ * HID_ + h * HD_;
  const u16* vtb = vt + (size_t)bh * HD_ * S_;

  // staging: waves 0,1 -> K (8KB/chunk), waves 2,3 -> V^T (8KB/chunk).
  // LDS dest linear; XOR swizzle pre-applied to the global source column.
  const u16* sp[4];
  int dj[4];
  u16* ldsbase;
  ptrdiff_t stride;
  if (wave < 2) {
    ldsbase = smem;                       // K: 32 s-rows x 256B
    stride = 32 * HID_;
#pragma unroll
    for (int i = 0; i < 4; ++i) {
      const int jj = wave * 4 + i;
      const int row = jj * 4 + (lane >> 4);
      const int cb = (lane & 15) * 16;
      const int cbp = cb ^ ((row & 7) << 4);
      sp[i] = kb + (size_t)row * HID_ + (cbp >> 1);
      dj[i] = jj * 512;
    }
  } else {
    ldsbase = smem + 8192;                // V^T: 128 d-rows x 64B
    stride = 32;
#pragma unroll
    for (int i = 0; i < 4; ++i) {
      const int jj = (wave - 2) * 4 + i;
      const int d = jj * 16 + (lane >> 2);
      const int cb = (lane & 3) * 16;
      const int cbp = cb ^ ((d & 3) << 4);
      sp[i] = vtb + (size_t)d * S_ + (cbp >> 1);
      dj[i] = jj * 512;
    }
  }
#define STAGE(cur)                                            \
  do {                                                        \
    _Pragma("unroll") for (int i_ = 0; i_ < 4; ++i_) {        \
      gload_lds16(sp[i_], ldsbase + (cur) * 4096 + dj[i_]);   \
      sp[i_] += stride;                                       \
    }                                                         \
  } while (0)

  STAGE(0);

  for (int s = tid; s < S_; s += 256)
    addend[s] = mask[b * S_ + s] ? 0.f : -1e30f;

  // Q fragments (B-operand of 32x32x16): col t = l31, k = hi*8 + j
  const u16* qrow = q + (size_t)(b * T_ + tw + l31) * HID_ + h * HD_;
  bf16x8 qf[8];
#pragma unroll
  for (int dc = 0; dc < 8; ++dc)
    qf[dc] = *(const bf16x8*)&qrow[dc * 16 + hi * 8];

  // K-read offsets (u16): row s = l31 (256B rows), col (dc*32+hi*16)^((s&7)<<4)
  int kofs[8];
#pragma unroll
  for (int dc = 0; dc < 8; ++dc)
    kofs[dc] = l31 * 128 + (((dc * 32 + hi * 16) ^ ((l31 & 7) << 4)) >> 1);
  // V-read offsets (u16): row d = db*32+l31 (64B rows), col (ks*32+hi*16)^((d&3)<<4)
  const int vcol0 = ((hi * 16) ^ ((l31 & 3) << 4)) >> 1;
  const int vcol1 = ((32 + hi * 16) ^ ((l31 & 3) << 4)) >> 1;

  float m_run = -1e30f, l_run = 0.f;
  f32x16 ct[4];
#pragma unroll
  for (int i = 0; i < 4; ++i)
#pragma unroll
    for (int r = 0; r < 16; ++r) ct[i][r] = 0.f;
  const float scale = 0.08838834764831845f;  // 1/sqrt(128)

  __syncthreads();   // buf0 staged, addend ready

  for (int it = 0; it < 16; ++it) {
    const int cur = it & 1;
    if (it < 15) STAGE(cur ^ 1);
    const int s0 = it * 32;
    const u16* kt = smem + cur * 4096;
    const u16* vl = smem + 8192 + cur * 4096;

    // QK^T: S^T[s][t], lane t=l31 holds s = (r&3) + 8*(r>>2) + 4*hi
    f32x16 st;
#pragma unroll
    for (int r = 0; r < 16; ++r) st[r] = 0.f;
    __builtin_amdgcn_s_setprio(1);
#pragma unroll
    for (int dc = 0; dc < 8; ++dc) {
      bf16x8 kf = *(const bf16x8*)&kt[kofs[dc]];
      st = mfma32(kf, qf[dc], st);
    }
    __builtin_amdgcn_s_setprio(0);

    // scale + mask
    float sc[16];
#pragma unroll
    for (int rq = 0; rq < 4; ++rq) {
      f4 ad = *(const f4*)&addend[s0 + rq * 8 + hi * 4];
#pragma unroll
      for (int m = 0; m < 4; ++m)
        sc[rq * 4 + m] = st[rq * 4 + m] * scale + ad[m];
    }
    // online softmax (defer-max, THR=8); pair (t,hi)/(t,hi^1) spans all 32 s
    float tm = sc[0];
#pragma unroll
    for (int i = 1; i < 16; ++i) tm = fmaxf(tm, sc[i]);
    tm = fmaxf(tm, __shfl_xor(tm, 32));
    const float nm = fmaxf(m_run, tm);
    if (!__all(nm - m_run <= 8.f)) {
      const float corr = __expf(m_run - nm);
      l_run *= corr;
#pragma unroll
      for (int db = 0; db < 4; ++db)
#pragma unroll
        for (int r = 0; r < 16; ++r) ct[db][r] *= corr;
      m_run = nm;
    }
    float p[16], ps = 0.f;
#pragma unroll
    for (int i = 0; i < 16; ++i) { p[i] = __expf(sc[i] - m_run); ps += p[i]; }
    ps += __shfl_xor(ps, 32);
    l_run += ps;

    // pack P into PV B-fragments fully in-register:
    // w[2q+n] = bf16 pair for s = q*8 + hi*4 + 2n {+0,+1}
    u32 w[8], x[8];
#pragma unroll
    for (int q2 = 0; q2 < 4; ++q2) {
      w[2 * q2]     = cvtpk(p[4 * q2],     p[4 * q2 + 1]);
      w[2 * q2 + 1] = cvtpk(p[4 * q2 + 2], p[4 * q2 + 3]);
    }
#pragma unroll
    for (int i = 0; i < 8; ++i) x[i] = __shfl_xor((int)w[i], 32);
    const u32x4 f0 = hi ? (u32x4){x[2], x[3], w[2], w[3]}
                        : (u32x4){w[0], w[1], x[0], x[1]};
    const u32x4 f1 = hi ? (u32x4){x[6], x[7], w[6], w[7]}
                        : (u32x4){w[4], w[5], x[4], x[5]};
    const bf16x8 pf0 = __builtin_bit_cast(bf16x8, f0);  // k-slot s0..s0+15
    const bf16x8 pf1 = __builtin_bit_cast(bf16x8, f1);  // k-slot s0+16..+31

    // PV: ctx^T[d][t] += V^T[d][s] P^T[s][t]
    __builtin_amdgcn_s_setprio(1);
#pragma unroll
    for (int db = 0; db < 4; ++db) {
      bf16x8 vf0 = *(const bf16x8*)&vl[db * 1024 + l31 * 32 + vcol0];
      ct[db] = mfma32(vf0, pf0, ct[db]);
      bf16x8 vf1 = *(const bf16x8*)&vl[db * 1024 + l31 * 32 + vcol1];
      ct[db] = mfma32(vf1, pf1, ct[db]);
    }
    __builtin_amdgcn_s_setprio(0);

    __syncthreads();
  }
#undef STAGE

  // epilogue: lane holds ctx^T[d = db*32 + (r&3)+8*(r>>2)+4*hi][t=l31];
  // transpose per-wave via stride-136 LDS then coalesced us8 row stores.
  const float gsig = 1.f / (1.f + __expf(-gate[0]));
  const float inv = gsig / l_run;
  u16* c_lds = smem + wave * 4352;    // 32 rows x 136 u16
#pragma unroll
  for (int db = 0; db < 4; ++db)
#pragma unroll
    for (int rq = 0; rq < 4; ++rq) {
      us4 o = { f2bf(ct[db][rq * 4 + 0] * inv), f2bf(ct[db][rq * 4 + 1] * inv),
                f2bf(ct[db][rq * 4 + 2] * inv), f2bf(ct[db][rq * 4 + 3] * inv) };
      *(us4*)&c_lds[l31 * 136 + db * 32 + rq * 8 + hi * 4] = o;
    }
  u16* crow = ctx + (size_t)(b * T_ + tw) * HID_ + h * HD_;
#pragma unroll
  for (int rep = 0; rep < 8; ++rep) {
    const int tt = (lane >> 4) + rep * 4;
    us8 valv = *(const us8*)&c_lds[tt * 136 + (lane & 15) * 8];
    *(us8*)&crow[(size_t)tt * HID_ + (lane & 15) * 8] = valv;
  }
}

// ---------------- launch ----------------
extern "C" void kernel_launch(void* const* d_in, const int* in_sizes, int n_in,
                              void* d_out, int out_size, void* d_ws, size_t ws_size,
                              hipStream_t stream) {
  (void)in_sizes; (void)n_in; (void)out_size; (void)ws_size;
  const float* hs   = (const float*)d_in[0];
  const float* nts  = (const float*)d_in[1];
  const int*   mask = (const int*)d_in[2];
  const float* qw   = (const float*)d_in[3];
  const float* qb   = (const float*)d_in[4];
  const float* kw   = (const float*)d_in[5];
  const float* kbi  = (const float*)d_in[6];
  const float* vw   = (const float*)d_in[7];
  const float* vbi  = (const float*)d_in[8];
  const float* ow   = (const float*)d_in[9];
  const float* obi  = (const float*)d_in[10];
  const float* gate = (const float*)d_in[11];
  float* out = (float*)d_out;

  char* w = (char*)d_ws;
  u16* h_bf   = (u16*)(w + 0);          // 33,554,432 B
  u16* n_bf   = (u16*)(w + 33554432);   //  4,194,304 B
  u16* qw_bf  = (u16*)(w + 37748736);   //  8,388,608 B
  u16* kw_bf  = (u16*)(w + 46137344);   //  4,194,304 B
  u16* vw_bf  = (u16*)(w + 50331648);   //  4,194,304 B
  u16* ow_bf  = (u16*)(w + 54525952);   //  8,388,608 B
  u16* q_bf   = (u16*)(w + 62914560);   // 33,554,432 B
  u16* k_bf   = (u16*)(w + 96468992);   //  8,388,608 B
  u16* v_bf   = (u16*)(w + 104857600);  //  8,388,608 B
  u16* vt_bf  = (u16*)(w + 113246208);  //  8,388,608 B  (end 121,634,816)
  u16* ctx_bf = h_bf;                   // alias: hidden_bf16 dead after Q-proj

  hipFuncSetAttribute(reinterpret_cast<const void*>(&gemm256<true>),
                      hipFuncAttributeMaxDynamicSharedMemorySize, 98304);
  hipFuncSetAttribute(reinterpret_cast<const void*>(&gemm256<false>),
                      hipFuncAttributeMaxDynamicSharedMemorySize, 98304);

  convert_all<<<dim3(2048), dim3(256), 0, stream>>>(
      hs, nts, qw, kw, vw, ow, h_bf, n_bf, qw_bf, kw_bf, vw_bf, ow_bf);
  gemm_bt<true><<<dim3(16, 16), dim3(256), 0, stream>>>(
      n_bf, kw_bf, kbi, k_bf, 2048, 2048, 1024);
  gemm_bt<true><<<dim3(16, 16), dim3(256), 0, stream>>>(
      n_bf, vw_bf, vbi, v_bf, 2048, 2048, 1024);
  transpose_v<<<dim3(16, 64, 4), dim3(256), 0, stream>>>(v_bf, vt_bf);
  gemm256<true><<<dim3(8, 32), dim3(512), 98304, stream>>>(
      h_bf, qw_bf, qb, q_bf, 8192, 2048, 2048);
  attn_fwd<<<dim3(16, 64), dim3(256), 0, stream>>>(
      q_bf, k_bf, vt_bf, mask, gate, ctx_bf);
  gemm256<false><<<dim3(8, 32), dim3(512), 98304, stream>>>(
      ctx_bf, ow_bf, obi, out, 8192, 2048, 2048);
}